// Round 7
// baseline (94.811 us; speedup 1.0000x reference)
//
#include <hip/hip_runtime.h>
#include <hip/hip_bf16.h>

typedef __attribute__((ext_vector_type(8))) short bf16x8;
typedef __attribute__((ext_vector_type(4))) float f32x4;
typedef __attribute__((ext_vector_type(16))) float f32x16;

#define NHID 256
#define NDIM 128
#define NB   512

__device__ __forceinline__ unsigned pk2bf(float a, float b) {
  float2 f; f.x = a; f.y = b;
  __hip_bfloat162 h = __float22bfloat162_rn(f);
  unsigned r;
  __builtin_memcpy(&r, &h, 4);
  return r;
}

// ---------------- setup (unchanged layouts) ----------------
// hx = x@Wx^T + b0, hy = y@Wy^T  (8 rows per block)
// W1/W2 -> bf16 fragment-major for 32x32x16 MFMA:
//   frag f = kt*8 + gtile  (kt = k>>4, gtile = g>>5), 1 KB each.
//   lane l = (g&31) + 32*((k>>3)&1) holds W[g][kt*16 + (l>>5)*8 .. +8] as 8 bf16 at l*16 bytes.
__global__ void k_setup(const float* __restrict__ x, const float* __restrict__ y,
                        const float* __restrict__ W0, const float* __restrict__ b0,
                        const float* __restrict__ W1, const float* __restrict__ W2,
                        float* __restrict__ hx, float* __restrict__ hy,
                        unsigned short* __restrict__ W1f, unsigned short* __restrict__ W2f) {
  int bid = blockIdx.x, tid = threadIdx.x;
  if (bid < 128) {
    int which = bid & 1;                 // 0: hx (+b0), 1: hy
    int rowbase = (bid >> 1) * 8;
    const float* in = which ? y : x;
    const f32x4* wr = (const f32x4*)(W0 + tid * (2 * NDIM) + which * NDIM);
    f32x4 sv[8];
#pragma unroll
    for (int r = 0; r < 8; ++r) sv[r] = f32x4{0.f, 0.f, 0.f, 0.f};
#pragma unroll 4
    for (int i = 0; i < NDIM / 4; ++i) {
      f32x4 b = wr[i];
#pragma unroll
      for (int r = 0; r < 8; ++r) {
        f32x4 a = *(const f32x4*)(in + (rowbase + r) * NDIM + i * 4);
        sv[r] += a * b;
      }
    }
    float bb = which ? 0.f : b0[tid];
    float* o = (which ? hy : hx) + rowbase * NHID + tid;
#pragma unroll
    for (int r = 0; r < 8; ++r)
      o[r * NHID] = sv[r][0] + sv[r][1] + sv[r][2] + sv[r][3] + bb;
  } else {
    int i = ((bid - 128) * 256 + tid) * 4;        // 2*65536 elements total
    const float* src = W1; unsigned short* dst = W1f; int j = i;
    if (i >= NHID * NHID) { src = W2; dst = W2f; j = i - NHID * NHID; }
    float4 v = *(const float4*)(src + j);
    int g = j >> 8, k0 = j & 255;                 // 4 consecutive k, same g
    int f = ((k0 >> 4) << 3) + (g >> 5);
    int l = (g & 31) + (((k0 >> 3) & 1) << 5);
    uint2 pk; pk.x = pk2bf(v.x, v.y); pk.y = pk2bf(v.z, v.w);
    *(uint2*)(dst + f * 512 + l * 8 + (k0 & 7)) = pk;
  }
}

// ---------------- main fused kernel: 64 pairs (8 a x 8 b) per block, 256 threads ----------------
// Two 32 KB h-buffers (h0 -> layer1 -> h1 -> layer2). Fragment-major h layout:
//   frag(kt, mt) at (kt*2 + mt)*1024 bytes (kt in [0,16), mt in [0,2)), lane's 16B at lane*16:
//   h[m = mt*32 + (lane&31)][k = kt*16 + (lane>>5)*8 .. +8].
// OWNERSHIP ROTATION: wave wv builds/epilogues exactly kt-group [4wv, 4wv+4) and its layer
// loops iterate kt starting at 4wv — the first 4 iterations touch only self-written
// fragments (no barrier; same-wave lgkmcnt ordering). One barrier per layer at j==3,
// one before the final out reduction. Fast waves drift ahead -> phases overlap.
__global__ __launch_bounds__(256, 2) void k_main(
    const float* __restrict__ hx, const float* __restrict__ hy,
    const unsigned short* __restrict__ W1f, const unsigned short* __restrict__ W2f,
    const float* __restrict__ bias1, const float* __restrict__ bias2,
    const float* __restrict__ w3, const float* __restrict__ b3,
    float* __restrict__ out) {
  __shared__ __align__(16) char h0b[32768];
  __shared__ __align__(16) char h1b[32768];

  const int tid = threadIdx.x;
  const int bid = blockIdx.x;
  const int a0i = (bid >> 6) * 8;    // 64 a-groups of 8 rows
  const int bb0 = (bid & 63) * 8;    // 64 b-groups of 8 rows

  const int lane = tid & 63, wv = tid >> 6;   // 4 waves
  const int c = lane & 31, l5 = lane >> 5;
  const int kt0 = wv * 4;                     // owned kt-group
  const f32x4 vzero = {0.f, 0.f, 0.f, 0.f};

  const unsigned short* fbW1 = W1f + wv * 1024 + lane * 8;  // + kt*4096 (ushort), +512 2nd gtile
  const unsigned short* fbW2 = W2f + wv * 1024 + lane * 8;

  // prime layer-1 A fragments (j = 0,1 -> kt0, kt0+1); latency hides under the build
  bf16x8 Aa[2], Ab[2];
  Aa[0] = *(const bf16x8*)(fbW1 + kt0 * 4096);
  Ab[0] = *(const bf16x8*)(fbW1 + kt0 * 4096 + 512);
  Aa[1] = *(const bf16x8*)(fbW1 + (kt0 + 1) * 4096);
  Ab[1] = *(const bf16x8*)(fbW1 + (kt0 + 1) * 4096 + 512);

  // ---- build OWN kt-group of h0: frags (kt0+ktL, mt), ktL in [0,4), mt in [0,2) ----
  // h0[m][k] = relu(hx'[a0i + m>>3][k] + hy[bb0 + (m&7)][k]),  m = mt*32 + c
  {
#pragma unroll
    for (int jj = 0; jj < 8; ++jj) {
      int ktL = jj >> 1, mt = jj & 1;
      int ktg = kt0 + ktL;
      int m = mt * 32 + c;
      const float* px = hx + (a0i + (m >> 3)) * NHID + ktg * 16 + l5 * 8;
      const float* py = hy + (bb0 + (m & 7)) * NHID + ktg * 16 + l5 * 8;
      f32x4 x0 = *(const f32x4*)(px);
      f32x4 x1 = *(const f32x4*)(px + 4);
      f32x4 y0 = *(const f32x4*)(py);
      f32x4 y1 = *(const f32x4*)(py + 4);
      f32x4 a = __builtin_elementwise_max(x0 + y0, vzero);
      f32x4 b = __builtin_elementwise_max(x1 + y1, vzero);
      uint4 pk;
      pk.x = pk2bf(a[0], a[1]);
      pk.y = pk2bf(a[2], a[3]);
      pk.z = pk2bf(b[0], b[1]);
      pk.w = pk2bf(b[2], b[3]);
      *(uint4*)(h0b + (ktg * 2 + mt) * 1024 + lane * 16) = pk;
    }
  }
  // own writes must be visible to own reads below (no barrier needed)
  asm volatile("s_waitcnt lgkmcnt(0)" ::: "memory");

  const char* h0l = h0b + lane * 16;
  const char* h1l = h1b + lane * 16;
  f32x16 acc[2][2];

  // ---- layer 1: rotated K-loop starting at own group; barrier after j==3 ----
#pragma unroll
  for (int gt = 0; gt < 2; ++gt)
#pragma unroll
    for (int mt = 0; mt < 2; ++mt)
#pragma unroll
      for (int e = 0; e < 16; ++e) acc[gt][mt][e] = 0.f;

#pragma unroll
  for (int j = 0; j < 16; ++j) {
    int ktj = (kt0 + j) & 15;
    bf16x8 B0 = *(const bf16x8*)(h0l + ktj * 2048);
    bf16x8 B1 = *(const bf16x8*)(h0l + ktj * 2048 + 1024);
    bf16x8 A0 = Aa[j & 1], A1 = Ab[j & 1];
    __builtin_amdgcn_s_setprio(1);
    acc[0][0] = __builtin_amdgcn_mfma_f32_32x32x16_bf16(A0, B0, acc[0][0], 0, 0, 0);
    acc[0][1] = __builtin_amdgcn_mfma_f32_32x32x16_bf16(A0, B1, acc[0][1], 0, 0, 0);
    acc[1][0] = __builtin_amdgcn_mfma_f32_32x32x16_bf16(A1, B0, acc[1][0], 0, 0, 0);
    acc[1][1] = __builtin_amdgcn_mfma_f32_32x32x16_bf16(A1, B1, acc[1][1], 0, 0, 0);
    __builtin_amdgcn_s_setprio(0);
    if (j + 2 < 16) {
      int kn = ((kt0 + j + 2) & 15) * 4096;
      Aa[j & 1] = *(const bf16x8*)(fbW1 + kn);
      Ab[j & 1] = *(const bf16x8*)(fbW1 + kn + 512);
    }
    if (j == 3) __syncthreads();     // all builds done before reading others' frags
  }

  // prime layer-2 A fragments (latency hides under the epilogue VALU)
  Aa[0] = *(const bf16x8*)(fbW2 + kt0 * 4096);
  Ab[0] = *(const bf16x8*)(fbW2 + kt0 * 4096 + 512);
  Aa[1] = *(const bf16x8*)(fbW2 + (kt0 + 1) * 4096);
  Ab[1] = *(const bf16x8*)(fbW2 + (kt0 + 1) * 4096 + 512);

  // ---- layer-1 epilogue: h1 = relu(acc + b1) -> OWN kt-group of h1b (no barrier!) ----
  // acc[gt][mt][r]: m = mt*32 + c, g = wv*64 + gt*32 + rg*8 + l5*4 + (r&3)  (rg = r>>2).
  // Dest frag f' = (g>>4)*2 + mt = (kt0 + gt*2 + (rg>>1))*2 + mt (own group!),
  //   lane slot = c + 32*(rg&1), byte +l5*8 (8B store of 4 bf16).
  {
#pragma unroll
    for (int gt = 0; gt < 2; ++gt) {
#pragma unroll
      for (int rg = 0; rg < 4; ++rg) {
        f32x4 bv = *(const f32x4*)(bias1 + wv * 64 + gt * 32 + rg * 8 + l5 * 4);
        char* wa = h1b + (c + ((rg & 1) << 5)) * 16 + l5 * 8;
        int fbase = (kt0 + gt * 2 + (rg >> 1)) * 2;
#pragma unroll
        for (int mt = 0; mt < 2; ++mt) {
          f32x16 v = acc[gt][mt];
          f32x4 t = {v[rg * 4 + 0], v[rg * 4 + 1], v[rg * 4 + 2], v[rg * 4 + 3]};
          t = __builtin_elementwise_max(t + bv, vzero);
          uint2 pk;
          pk.x = pk2bf(t[0], t[1]);
          pk.y = pk2bf(t[2], t[3]);
          *(uint2*)(wa + (fbase + mt) * 1024) = pk;
        }
      }
    }
  }
  asm volatile("s_waitcnt lgkmcnt(0)" ::: "memory");

  // ---- layer 2: rotated K-loop over h1b; barrier after j==3 covers all epilogues ----
#pragma unroll
  for (int gt = 0; gt < 2; ++gt)
#pragma unroll
    for (int mt = 0; mt < 2; ++mt)
#pragma unroll
      for (int e = 0; e < 16; ++e) acc[gt][mt][e] = 0.f;

#pragma unroll
  for (int j = 0; j < 16; ++j) {
    int ktj = (kt0 + j) & 15;
    bf16x8 B0 = *(const bf16x8*)(h1l + ktj * 2048);
    bf16x8 B1 = *(const bf16x8*)(h1l + ktj * 2048 + 1024);
    bf16x8 A0 = Aa[j & 1], A1 = Ab[j & 1];
    __builtin_amdgcn_s_setprio(1);
    acc[0][0] = __builtin_amdgcn_mfma_f32_32x32x16_bf16(A0, B0, acc[0][0], 0, 0, 0);
    acc[0][1] = __builtin_amdgcn_mfma_f32_32x32x16_bf16(A0, B1, acc[0][1], 0, 0, 0);
    acc[1][0] = __builtin_amdgcn_mfma_f32_32x32x16_bf16(A1, B0, acc[1][0], 0, 0, 0);
    acc[1][1] = __builtin_amdgcn_mfma_f32_32x32x16_bf16(A1, B1, acc[1][1], 0, 0, 0);
    __builtin_amdgcn_s_setprio(0);
    if (j + 2 < 16) {
      int kn = ((kt0 + j + 2) & 15) * 4096;
      Aa[j & 1] = *(const bf16x8*)(fbW2 + kn);
      Ab[j & 1] = *(const bf16x8*)(fbW2 + kn + 512);
    }
    if (j == 3) __syncthreads();     // all epilogues done before reading others' frags
  }

  // ---- head: out = relu(acc + b2) . w3, reduced over g ----
  float s[2];
  {
    f32x4 sv[2] = {vzero, vzero};
#pragma unroll
    for (int gt = 0; gt < 2; ++gt) {
#pragma unroll
      for (int rg = 0; rg < 4; ++rg) {
        int g0 = wv * 64 + gt * 32 + rg * 8 + l5 * 4;
        f32x4 bv  = *(const f32x4*)(bias2 + g0);
        f32x4 wvv = *(const f32x4*)(w3 + g0);
#pragma unroll
        for (int mt = 0; mt < 2; ++mt) {
          f32x16 v = acc[gt][mt];
          f32x4 t = {v[rg * 4 + 0], v[rg * 4 + 1], v[rg * 4 + 2], v[rg * 4 + 3]};
          t = __builtin_elementwise_max(t + bv, vzero);
          sv[mt] += t * wvv;
        }
      }
    }
#pragma unroll
    for (int mt = 0; mt < 2; ++mt) {
      float t = sv[mt][0] + sv[mt][1] + sv[mt][2] + sv[mt][3];
      t += __shfl_xor(t, 32);            // combine the two l5 halves (different g-quads)
      s[mt] = t;
    }
  }

  // stage partials in h0b (dead after layer 1; all waves past their h0 reads by now)
  float* stg = (float*)h0b;              // [4 waves][64 m]
  if (l5 == 0) {
#pragma unroll
    for (int mt = 0; mt < 2; ++mt) stg[wv * 64 + mt * 32 + c] = s[mt];
  }
  __syncthreads();

  if (tid < 64) {
    float v = b3[0];
#pragma unroll
    for (int w = 0; w < 4; ++w) v += stg[w * 64 + tid];
    out[(a0i + (tid >> 3)) * NB + bb0 + (tid & 7)] = v;
  }
}

extern "C" void kernel_launch(void* const* d_in, const int* in_sizes, int n_in,
                              void* d_out, int out_size, void* d_ws, size_t ws_size,
                              hipStream_t stream) {
  const float* x  = (const float*)d_in[0];
  const float* y  = (const float*)d_in[1];
  const float* W0 = (const float*)d_in[2];
  const float* b0 = (const float*)d_in[3];
  const float* W1 = (const float*)d_in[4];
  const float* b1 = (const float*)d_in[5];
  const float* W2 = (const float*)d_in[6];
  const float* b2 = (const float*)d_in[7];
  const float* W3 = (const float*)d_in[8];
  const float* b3 = (const float*)d_in[9];
  float* out = (float*)d_out;

  char* ws = (char*)d_ws;
  float* hx = (float*)ws;                               // 512*256*4 = 512 KB
  float* hy = (float*)(ws + 524288);                    // 512 KB
  unsigned short* W1f = (unsigned short*)(ws + 1048576);          // 128 KB
  unsigned short* W2f = (unsigned short*)(ws + 1048576 + 131072); // 128 KB

  k_setup<<<dim3(256), dim3(256), 0, stream>>>(x, y, W0, b0, W1, W2, hx, hy, W1f, W2f);
  k_main<<<dim3(4096), dim3(256), 0, stream>>>(hx, hy, W1f, W2f, b1, b2, W3, b3, out);
}